// Round 1
// 783.177 us; speedup vs baseline: 1.0572x; 1.0572x over previous
//
#include <hip/hip_runtime.h>
#include <stdint.h>

// CrossAttention seq-len-1: softmax over singleton axis == 1, so attention
// reduces to   attn = x_other @ (out_w @ wv).T + (out_w @ bv + out_b).
// Pipeline per stream: combined-GEMM -> add+LN -> relu-GEMM -> GEMM(->d_out) -> add+LN in-place.
// All GEMMs bf16 MFMA (16x16x32), fp32 accumulate. Threshold is bf16-floor (0.111).
//
// GEMM K-loop: triple-buffered LDS, prefetch depth 2, counted s_waitcnt vmcnt(4)
// (never 0 in the steady state) + raw s_barrier fused in one asm block. This keeps
// 8 global_load_lds in flight across barriers instead of draining per K-step.

#define E 512
#define LNEPS 1e-5f

typedef unsigned short u16;
using u16x8   = __attribute__((ext_vector_type(8))) u16;
using shortx8 = __attribute__((ext_vector_type(8))) short;
using floatx4 = __attribute__((ext_vector_type(4))) float;

__device__ __forceinline__ float bf2f(u16 u) {
  uint32_t x = ((uint32_t)u) << 16;
  return __builtin_bit_cast(float, x);
}
__device__ __forceinline__ u16 f2bf(float f) {  // round-to-nearest-even
  uint32_t x = __builtin_bit_cast(uint32_t, f);
  x += 0x7fffu + ((x >> 16) & 1u);
  return (u16)(x >> 16);
}

__device__ __forceinline__ void gl_lds16(const u16* g, u16* l) {
  // async global->LDS, 16B per lane; LDS dest = wave-uniform base + lane*16
  __builtin_amdgcn_global_load_lds(
      (__attribute__((address_space(1))) uint32_t*)g,
      (__attribute__((address_space(3))) uint32_t*)l, 16, 0, 0);
}

// C[m,n] = sum_k A[m,k]*W[n,k] + bias[n]   (A: MxK bf16, W: NxK bf16 row-major)
// 128x128 block tile, BK=32, 4 waves each 64x64 (4x4 MFMA 16x16x32 tiles).
template <bool RELU, bool OUTF32>
__global__ __launch_bounds__(256) void gemm_bt(const u16* __restrict__ A,
                                               const u16* __restrict__ W,
                                               const float* __restrict__ bias,
                                               void* __restrict__ Cout,
                                               int M, int N, int K, int ldc) {
  // 3 buffers x (A 4096 + B 4096) u16 = 48 KB
  __shared__ u16 sbuf[3 * 8192];
  const int tid  = threadIdx.x;
  const int wave = tid >> 6;
  const int lane = tid & 63;
  const int m0 = blockIdx.x * 128;
  const int n0 = blockIdx.y * 128;
  const int wm = (wave >> 1) * 64;
  const int wn = (wave & 1) * 64;
  const int fm   = lane & 15;
  const int quad = lane >> 4;

  const floatx4 zero = {0.f, 0.f, 0.f, 0.f};
  floatx4 acc[4][4];
#pragma unroll
  for (int i = 0; i < 4; ++i)
#pragma unroll
    for (int j = 0; j < 4; ++j) acc[i][j] = zero;

  // staging map: elem o = wave*512 + lane*8 (+2048 for second half); row=o/32, col=o%32
  const int o0 = wave * 512 + lane * 8;
  const int r0 = o0 >> 5;
  const int c0 = o0 & 31;
  const u16* Ap = A + (size_t)(m0 + r0) * K + c0;
  const u16* Wp = W + (size_t)(n0 + r0) * K + c0;
  const size_t skip = (size_t)64 * K;  // +64 rows for second half
  const int dst = wave * 512;          // u16 elems into buffer
  const int nt = K >> 5;               // number of BK=32 tiles (>= 16 for all launches)

  auto STAGE = [&](const u16* ap, const u16* wp, int b) {
    u16* base = sbuf + b * 8192;
    gl_lds16(ap, base + dst);
    gl_lds16(ap + skip, base + dst + 2048);
    gl_lds16(wp, base + 4096 + dst);
    gl_lds16(wp + skip, base + 4096 + dst + 2048);
  };
  auto COMPUTE = [&](int b) {
    const u16* bA = sbuf + b * 8192;
    const u16* bB = bA + 4096;
    shortx8 af[4], bf[4];
#pragma unroll
    for (int i = 0; i < 4; ++i) {
      af[i] = *(const shortx8*)(bA + (wm + i * 16 + fm) * 32 + quad * 8);
      bf[i] = *(const shortx8*)(bB + (wn + i * 16 + fm) * 32 + quad * 8);
    }
#pragma unroll
    for (int i = 0; i < 4; ++i)
#pragma unroll
      for (int j = 0; j < 4; ++j)
        acc[i][j] = __builtin_amdgcn_mfma_f32_16x16x32_bf16(af[i], bf[j], acc[i][j], 0, 0, 0);
  };

  // prologue: tiles 0,1 -> buffers 0,1 (8 loads in flight)
  STAGE(Ap, Wp, 0);
  STAGE(Ap + 32, Wp + 32, 1);
  const u16* As = Ap + 64;
  const u16* Ws = Wp + 64;
  int sb = 2, cb = 0;

  for (int t = 0; t < nt - 1; ++t) {
    // retire tile t's 4 loads (leave tile t+1's 4 in flight), then sync.
    // single asm block so no LDS read can slip between the waitcnt and barrier.
    asm volatile("s_waitcnt vmcnt(4)\n\ts_barrier" ::: "memory");
    if (t < nt - 2) {
      // stage tile t+2 into the buffer read at iter t-1 (all waves past barrier)
      STAGE(As, Ws, sb);
      As += 32;
      Ws += 32;
      sb = (sb == 2) ? 0 : sb + 1;
    }
    COMPUTE(cb);
    cb = (cb == 2) ? 0 : cb + 1;
  }
  asm volatile("s_waitcnt vmcnt(0)\n\ts_barrier" ::: "memory");
  COMPUTE(cb);

  // epilogue: C/D layout col=lane&15, row=quad*4+reg  (m89/m91 verified)
#pragma unroll
  for (int j = 0; j < 4; ++j) {
    const int col = n0 + wn + j * 16 + fm;
    const float bj = bias ? bias[col] : 0.f;
#pragma unroll
    for (int i = 0; i < 4; ++i) {
      const int rb = m0 + wm + i * 16 + quad * 4;
#pragma unroll
      for (int r = 0; r < 4; ++r) {
        float v = acc[i][j][r] + bj;
        if (RELU) v = fmaxf(v, 0.f);
        if (OUTF32)
          ((float*)Cout)[(size_t)(rb + r) * ldc + col] = v;
        else
          ((u16*)Cout)[(size_t)(rb + r) * ldc + col] = f2bf(v);
      }
    }
  }
}

// MODE 0: out_bf16[row*E] = LN(resid_f32[row*E] + add_bf16[row*E])
// MODE 1: out_f32[row*ld] = LN(resid_bf16[row*E] + add_f32[row*ld])   (in-place on d_out ok)
// one wave per row of 512; lane handles 8 consecutive elements
template <int MODE>
__global__ __launch_bounds__(256) void ln_add_kernel(const void* __restrict__ resid,
                                                     const void* __restrict__ addv,
                                                     const float* __restrict__ g,
                                                     const float* __restrict__ b,
                                                     void* __restrict__ outp, int ld) {
  const int wave = threadIdx.x >> 6;
  const int lane = threadIdx.x & 63;
  const size_t row = (size_t)blockIdx.x * 4 + wave;
  const int col = lane * 8;
  float x[8];
  if (MODE == 0) {
    const float* rp = (const float*)resid + row * E + col;
    const u16x8 a = *(const u16x8*)((const u16*)addv + row * E + col);
    const float4 r0 = *(const float4*)rp;
    const float4 r1 = *(const float4*)(rp + 4);
    x[0] = r0.x + bf2f(a[0]); x[1] = r0.y + bf2f(a[1]);
    x[2] = r0.z + bf2f(a[2]); x[3] = r0.w + bf2f(a[3]);
    x[4] = r1.x + bf2f(a[4]); x[5] = r1.y + bf2f(a[5]);
    x[6] = r1.z + bf2f(a[6]); x[7] = r1.w + bf2f(a[7]);
  } else {
    const u16x8 a = *(const u16x8*)((const u16*)resid + row * E + col);
    const float* ap = (const float*)addv + row * ld + col;
    const float4 r0 = *(const float4*)ap;
    const float4 r1 = *(const float4*)(ap + 4);
    x[0] = r0.x + bf2f(a[0]); x[1] = r0.y + bf2f(a[1]);
    x[2] = r0.z + bf2f(a[2]); x[3] = r0.w + bf2f(a[3]);
    x[4] = r1.x + bf2f(a[4]); x[5] = r1.y + bf2f(a[5]);
    x[6] = r1.z + bf2f(a[6]); x[7] = r1.w + bf2f(a[7]);
  }
  float s = 0.f, sq = 0.f;
#pragma unroll
  for (int i = 0; i < 8; ++i) {
    s += x[i];
    sq += x[i] * x[i];
  }
#pragma unroll
  for (int off = 32; off > 0; off >>= 1) {
    s += __shfl_xor(s, off);
    sq += __shfl_xor(sq, off);
  }
  const float mean = s * (1.f / E);
  const float var = sq * (1.f / E) - mean * mean;
  const float rs = rsqrtf(var + LNEPS);
  const float4 g0 = *(const float4*)(g + col);
  const float4 g1 = *(const float4*)(g + col + 4);
  const float4 b0 = *(const float4*)(b + col);
  const float4 b1 = *(const float4*)(b + col + 4);
  float y[8];
  y[0] = (x[0] - mean) * rs * g0.x + b0.x;
  y[1] = (x[1] - mean) * rs * g0.y + b0.y;
  y[2] = (x[2] - mean) * rs * g0.z + b0.z;
  y[3] = (x[3] - mean) * rs * g0.w + b0.w;
  y[4] = (x[4] - mean) * rs * g1.x + b1.x;
  y[5] = (x[5] - mean) * rs * g1.y + b1.y;
  y[6] = (x[6] - mean) * rs * g1.z + b1.z;
  y[7] = (x[7] - mean) * rs * g1.w + b1.w;
  if (MODE == 0) {
    u16x8 o;
#pragma unroll
    for (int i = 0; i < 8; ++i) o[i] = f2bf(y[i]);
    *(u16x8*)((u16*)outp + row * E + col) = o;
  } else {
    float* op = (float*)outp + row * ld + col;
    *(float4*)op = make_float4(y[0], y[1], y[2], y[3]);
    *(float4*)(op + 4) = make_float4(y[4], y[5], y[6], y[7]);
  }
}

__global__ __launch_bounds__(256) void cast_kernel(const float* __restrict__ in,
                                                   u16* __restrict__ out) {
  const size_t i = ((size_t)blockIdx.x * 256 + threadIdx.x) * 8;
  const float4 a = *(const float4*)(in + i);
  const float4 c = *(const float4*)(in + i + 4);
  u16x8 o;
  o[0] = f2bf(a.x); o[1] = f2bf(a.y); o[2] = f2bf(a.z); o[3] = f2bf(a.w);
  o[4] = f2bf(c.x); o[5] = f2bf(c.y); o[6] = f2bf(c.z); o[7] = f2bf(c.w);
  *(u16x8*)(out + i) = o;
}

// out[k][j] = bf16(in[j][k]) for ExE
__global__ __launch_bounds__(256) void transpose_cast_kernel(const float* __restrict__ in,
                                                             u16* __restrict__ out) {
  __shared__ float t[32][33];
  const int bx = blockIdx.x * 32;
  const int by = blockIdx.y * 32;
  const int x = threadIdx.x & 31;
  const int y0 = threadIdx.x >> 5;
#pragma unroll
  for (int y = y0; y < 32; y += 8) t[y][x] = in[(size_t)(by + y) * E + bx + x];
  __syncthreads();
#pragma unroll
  for (int y = y0; y < 32; y += 8) out[(size_t)(bx + y) * E + by + x] = f2bf(t[x][y]);
}

// bc[n] = dot(outw[n,:], bv) + outb[n]
__global__ __launch_bounds__(256) void combine_bias_kernel(const float* __restrict__ outw,
                                                           const float* __restrict__ bv,
                                                           const float* __restrict__ outb,
                                                           float* __restrict__ bc) {
  const int n = blockIdx.x * 256 + threadIdx.x;
  const float* wr = outw + (size_t)n * E;
  float s = 0.f;
  for (int j = 0; j < E; j += 4) {
    const float4 w4 = *(const float4*)(wr + j);
    const float4 v4 = *(const float4*)(bv + j);
    s += w4.x * v4.x + w4.y * v4.y + w4.z * v4.z + w4.w * v4.w;
  }
  bc[n] = s + outb[n];
}

extern "C" void kernel_launch(void* const* d_in, const int* in_sizes, int n_in,
                              void* d_out, int out_size, void* d_ws, size_t ws_size,
                              hipStream_t stream) {
  const float* dna      = (const float*)d_in[0];
  const float* mol      = (const float*)d_in[1];
  const float* a1_in_w  = (const float*)d_in[2];
  const float* a1_in_b  = (const float*)d_in[3];
  const float* a1_out_w = (const float*)d_in[4];
  const float* a1_out_b = (const float*)d_in[5];
  const float* a2_in_w  = (const float*)d_in[6];
  const float* a2_in_b  = (const float*)d_in[7];
  const float* a2_out_w = (const float*)d_in[8];
  const float* a2_out_b = (const float*)d_in[9];
  const float* ln1_g = (const float*)d_in[10];
  const float* ln1_b = (const float*)d_in[11];
  const float* ln2_g = (const float*)d_in[12];
  const float* ln2_b = (const float*)d_in[13];
  const float* ln3_g = (const float*)d_in[14];
  const float* ln3_b = (const float*)d_in[15];
  const float* ln4_g = (const float*)d_in[16];
  const float* ln4_b = (const float*)d_in[17];
  const float* f1_w1 = (const float*)d_in[18];
  const float* f1_b1 = (const float*)d_in[19];
  const float* f1_w2 = (const float*)d_in[20];
  const float* f1_b2 = (const float*)d_in[21];
  const float* f2_w1 = (const float*)d_in[22];
  const float* f2_b1 = (const float*)d_in[23];
  const float* f2_w2 = (const float*)d_in[24];
  const float* f2_b2 = (const float*)d_in[25];

  const int M = in_sizes[0] / E;  // 32768

  char* ws = (char*)d_ws;
  auto bump = [&](size_t sz) {
    char* p = ws;
    ws += (sz + 255) & ~(size_t)255;
    return p;
  };
  u16* wvT1   = (u16*)bump((size_t)E * E * 2);
  u16* wvT2   = (u16*)bump((size_t)E * E * 2);
  u16* outw1b = (u16*)bump((size_t)E * E * 2);
  u16* outw2b = (u16*)bump((size_t)E * E * 2);
  u16* Wc1    = (u16*)bump((size_t)E * E * 2);
  u16* Wc2    = (u16*)bump((size_t)E * E * 2);
  u16* fw11   = (u16*)bump((size_t)2 * E * E * 2);
  u16* fw12   = (u16*)bump((size_t)2 * E * E * 2);
  u16* fw21   = (u16*)bump((size_t)2 * E * E * 2);
  u16* fw22   = (u16*)bump((size_t)2 * E * E * 2);
  float* bc1  = (float*)bump(E * 4);
  float* bc2  = (float*)bump(E * 4);
  u16* X1 = (u16*)bump((size_t)M * E * 2);      // dna_bf, later y1
  u16* X2 = (u16*)bump((size_t)M * E * 2);      // mol_bf, later y2
  u16* Hb = (u16*)bump((size_t)M * 2 * E * 2);  // attnA|attnB, later FFN hidden
  u16* H0 = Hb;
  u16* H1 = Hb + (size_t)M * E;
  float* out_f = (float*)d_out;  // M x 2E, left=dna stream, right=mol stream

  // ---- weight prep (runs every call; ~7 MB of ws) ----
  transpose_cast_kernel<<<dim3(16, 16), 256, 0, stream>>>(a1_in_w + 2 * E * E, wvT1);
  transpose_cast_kernel<<<dim3(16, 16), 256, 0, stream>>>(a2_in_w + 2 * E * E, wvT2);
  cast_kernel<<<E * E / 2048, 256, 0, stream>>>(a1_out_w, outw1b);
  cast_kernel<<<E * E / 2048, 256, 0, stream>>>(a2_out_w, outw2b);
  cast_kernel<<<2 * E * E / 2048, 256, 0, stream>>>(f1_w1, fw11);
  cast_kernel<<<2 * E * E / 2048, 256, 0, stream>>>(f1_w2, fw12);
  cast_kernel<<<2 * E * E / 2048, 256, 0, stream>>>(f2_w1, fw21);
  cast_kernel<<<2 * E * E / 2048, 256, 0, stream>>>(f2_w2, fw22);
  combine_bias_kernel<<<2, 256, 0, stream>>>(a1_out_w, a1_in_b + 2 * E, a1_out_b, bc1);
  combine_bias_kernel<<<2, 256, 0, stream>>>(a2_out_w, a2_in_b + 2 * E, a2_out_b, bc2);
  // Wc[n,k] = sum_j out_w[n,j] * wv[j,k]  via gemm_bt(out_w, wv^T)
  gemm_bt<false, false><<<dim3(4, 4), 256, 0, stream>>>(outw1b, wvT1, nullptr, Wc1, E, E, E, E);
  gemm_bt<false, false><<<dim3(4, 4), 256, 0, stream>>>(outw2b, wvT2, nullptr, Wc2, E, E, E, E);

  // ---- activations ----
  cast_kernel<<<(int)((size_t)M * E / 2048), 256, 0, stream>>>(dna, X1);
  cast_kernel<<<(int)((size_t)M * E / 2048), 256, 0, stream>>>(mol, X2);
  // attn (softmax==1 -> pure projection with combined weights)
  gemm_bt<false, false><<<dim3(M / 128, 4), 256, 0, stream>>>(X2, Wc1, bc1, H0, M, E, E, E);
  gemm_bt<false, false><<<dim3(M / 128, 4), 256, 0, stream>>>(X1, Wc2, bc2, H1, M, E, E, E);
  // y = LN(x + attn)  (overwrites the now-dead bf16 input casts)
  ln_add_kernel<0><<<M / 4, 256, 0, stream>>>(dna, H0, ln1_g, ln1_b, X1, E);
  ln_add_kernel<0><<<M / 4, 256, 0, stream>>>(mol, H1, ln2_g, ln2_b, X2, E);
  // stream A FFN + final LN (in-place on d_out left half)
  gemm_bt<true, false><<<dim3(M / 128, 8), 256, 0, stream>>>(X1, fw11, f1_b1, Hb, M, 2 * E, E, 2 * E);
  gemm_bt<false, true><<<dim3(M / 128, 4), 256, 0, stream>>>(Hb, fw12, f1_b2, out_f, M, E, 2 * E, 2 * E);
  ln_add_kernel<1><<<M / 4, 256, 0, stream>>>(X1, out_f, ln3_g, ln3_b, out_f, 2 * E);
  // stream B FFN + final LN (in-place on d_out right half)
  gemm_bt<true, false><<<dim3(M / 128, 8), 256, 0, stream>>>(X2, fw21, f2_b1, Hb, M, 2 * E, E, 2 * E);
  gemm_bt<false, true><<<dim3(M / 128, 4), 256, 0, stream>>>(Hb, fw22, f2_b2, out_f + E, M, E, 2 * E, 2 * E);
  ln_add_kernel<1><<<M / 4, 256, 0, stream>>>(X2, out_f + E, ln4_g, ln4_b, out_f + E, 2 * E);
}

// Round 3
// 747.569 us; speedup vs baseline: 1.1076x; 1.0476x over previous
//
#include <hip/hip_runtime.h>
#include <stdint.h>

// CrossAttention seq-len-1: softmax over singleton axis == 1, so attention
// reduces to   attn = x_other @ (out_w @ wv).T + (out_w @ bv + out_b).
// Pipeline per stream: combined-GEMM -> add+LN -> relu-GEMM -> GEMM(->d_out) -> add+LN in-place.
// All GEMMs bf16 MFMA (16x16x32), fp32 accumulate. Threshold is bf16-floor (0.111).
//
// GEMM: 256x128 block tile, 4 waves each 64x128 (M_rep=4 x N_rep=8 MFMA frags).
// Rationale: 12KB LDS read per 32 MFMA (375 B/MFMA) vs 512 B/MFMA for the old
// 64x64 wave tile -- the K-loop is LDS-BW-bound, so reuse per LDS byte is the lever.
// K-loop: triple-buffered LDS (3 x 24KB), prefetch depth 2, counted s_waitcnt
// vmcnt(6) (never 0 in steady state) + raw s_barrier fused in one asm block.
// Grid: blockIdx.x = N-tile (fastest), blockIdx.y = M-tile so co-resident blocks
// span all N-tiles of few M-panels -> A fetched ~once from HBM (L2 reuse).
// NOTE: no LDS swizzle -- fragment reads are contiguous 1KB/wave; the ~4cy/read
// SQ_LDS_BANK_CONFLICT is intrinsic to ds_read_b128 (m134), not layout-induced.

#define E 512
#define LNEPS 1e-5f

typedef unsigned short u16;
using u16x8   = __attribute__((ext_vector_type(8))) u16;
using shortx8 = __attribute__((ext_vector_type(8))) short;
using floatx4 = __attribute__((ext_vector_type(4))) float;

__device__ __forceinline__ float bf2f(u16 u) {
  uint32_t x = ((uint32_t)u) << 16;
  return __builtin_bit_cast(float, x);
}
__device__ __forceinline__ u16 f2bf(float f) {  // round-to-nearest-even
  uint32_t x = __builtin_bit_cast(uint32_t, f);
  x += 0x7fffu + ((x >> 16) & 1u);
  return (u16)(x >> 16);
}

__device__ __forceinline__ void gl_lds16(const u16* g, u16* l) {
  // async global->LDS, 16B per lane; LDS dest = wave-uniform base + lane*16
  __builtin_amdgcn_global_load_lds(
      (__attribute__((address_space(1))) uint32_t*)g,
      (__attribute__((address_space(3))) uint32_t*)l, 16, 0, 0);
}

// C[m,n] = sum_k A[m,k]*W[n,k] + bias[n]   (A: MxK bf16, W: NxK bf16 row-major)
// 256x128 block tile, BK=32, 4 waves each 64x128.
template <bool RELU, bool OUTF32>
__global__ __launch_bounds__(256) void gemm_bt(const u16* __restrict__ A,
                                               const u16* __restrict__ W,
                                               const float* __restrict__ bias,
                                               void* __restrict__ Cout,
                                               int M, int N, int K, int ldc) {
  // 3 buffers x (A 256x32 = 16KB + B 128x32 = 8KB) = 72 KB
  __shared__ u16 sbuf[3 * 12288];
  const int tid  = threadIdx.x;
  const int wave = tid >> 6;
  const int lane = tid & 63;
  const int m0 = blockIdx.y * 256;   // M-tile on y
  const int n0 = blockIdx.x * 128;   // N-tile on x (fastest -> A-panel L2 reuse)
  const int wm = wave * 64;
  const int fm   = lane & 15;
  const int quad = lane >> 4;

  const floatx4 zero = {0.f, 0.f, 0.f, 0.f};
  floatx4 acc[4][8];
#pragma unroll
  for (int i = 0; i < 4; ++i)
#pragma unroll
    for (int j = 0; j < 8; ++j) acc[i][j] = zero;

  // staging map (linear LDS, 16B/lane): issue covers 16 rows x 32 cols.
  // A: wave stages rows [wave*64, wave*64+64) via 4 issues; B: rows [wave*32, +32) via 2.
  const int r4 = lane >> 2;          // 0..15
  const int c0 = (lane & 3) << 3;    // 0,8,16,24
  const u16* ApA = A + (size_t)(m0 + wave * 64 + r4) * K + c0;
  const u16* WpB = W + (size_t)(n0 + wave * 32 + r4) * K + c0;
  const size_t row16 = (size_t)16 * K;
  const int nt = K >> 5;             // BK=32 tiles (16 or 32 here)

  auto STAGE = [&](const u16* ap, const u16* wp, int b) {
    u16* base = sbuf + b * 12288;
#pragma unroll
    for (int q = 0; q < 4; ++q)
      gl_lds16(ap + (size_t)q * row16, base + (wave * 4 + q) * 512);
#pragma unroll
    for (int q = 0; q < 2; ++q)
      gl_lds16(wp + (size_t)q * row16, base + 8192 + (wave * 2 + q) * 512);
  };
  auto COMPUTE = [&](int b) {
    const u16* bA = sbuf + b * 12288;
    const u16* bB = bA + 8192;
    shortx8 af[4];
#pragma unroll
    for (int i = 0; i < 4; ++i)
      af[i] = *(const shortx8*)(bA + (wm + i * 16 + fm) * 32 + quad * 8);
#pragma unroll
    for (int j = 0; j < 8; ++j) {
      const shortx8 bf = *(const shortx8*)(bB + (j * 16 + fm) * 32 + quad * 8);
#pragma unroll
      for (int i = 0; i < 4; ++i)
        acc[i][j] = __builtin_amdgcn_mfma_f32_16x16x32_bf16(af[i], bf, acc[i][j], 0, 0, 0);
    }
  };

  // prologue: tiles 0,1 -> buffers 0,1 (12 loads in flight)
  STAGE(ApA, WpB, 0);
  STAGE(ApA + 32, WpB + 32, 1);
  const u16* As = ApA + 64;
  const u16* Ws = WpB + 64;
  int sb = 2, cb = 0;

  for (int t = 0; t < nt - 1; ++t) {
    // retire tile t's 6 loads (leave tile t+1's 6 in flight), then sync.
    // single asm block so no LDS read can slip between the waitcnt and barrier.
    asm volatile("s_waitcnt vmcnt(6)\n\ts_barrier" ::: "memory");
    if (t < nt - 2) {
      STAGE(As, Ws, sb);
      As += 32;
      Ws += 32;
      sb = (sb == 2) ? 0 : sb + 1;
    }
    COMPUTE(cb);
    cb = (cb == 2) ? 0 : cb + 1;
  }
  asm volatile("s_waitcnt vmcnt(0)\n\ts_barrier" ::: "memory");
  COMPUTE(cb);

  // epilogue: C/D layout col=lane&15, row=quad*4+reg  (m89/m91 verified)
#pragma unroll
  for (int j = 0; j < 8; ++j) {
    const int col = n0 + j * 16 + fm;
    const float bj = bias ? bias[col] : 0.f;
#pragma unroll
    for (int i = 0; i < 4; ++i) {
      const int rb = m0 + wm + i * 16 + quad * 4;
#pragma unroll
      for (int r = 0; r < 4; ++r) {
        float v = acc[i][j][r] + bj;
        if (RELU) v = fmaxf(v, 0.f);
        if (OUTF32)
          ((float*)Cout)[(size_t)(rb + r) * ldc + col] = v;
        else
          ((u16*)Cout)[(size_t)(rb + r) * ldc + col] = f2bf(v);
      }
    }
  }
}

// MODE 0: out_bf16[row*E] = LN(resid_f32[row*E] + add_bf16[row*E])
// MODE 1: out_f32[row*ld] = LN(resid_bf16[row*E] + add_f32[row*ld])   (in-place on d_out ok)
// one wave per row of 512; lane handles 8 consecutive elements
template <int MODE>
__global__ __launch_bounds__(256) void ln_add_kernel(const void* __restrict__ resid,
                                                     const void* __restrict__ addv,
                                                     const float* __restrict__ g,
                                                     const float* __restrict__ b,
                                                     void* __restrict__ outp, int ld) {
  const int wave = threadIdx.x >> 6;
  const int lane = threadIdx.x & 63;
  const size_t row = (size_t)blockIdx.x * 4 + wave;
  const int col = lane * 8;
  float x[8];
  if (MODE == 0) {
    const float* rp = (const float*)resid + row * E + col;
    const u16x8 a = *(const u16x8*)((const u16*)addv + row * E + col);
    const float4 r0 = *(const float4*)rp;
    const float4 r1 = *(const float4*)(rp + 4);
    x[0] = r0.x + bf2f(a[0]); x[1] = r0.y + bf2f(a[1]);
    x[2] = r0.z + bf2f(a[2]); x[3] = r0.w + bf2f(a[3]);
    x[4] = r1.x + bf2f(a[4]); x[5] = r1.y + bf2f(a[5]);
    x[6] = r1.z + bf2f(a[6]); x[7] = r1.w + bf2f(a[7]);
  } else {
    const u16x8 a = *(const u16x8*)((const u16*)resid + row * E + col);
    const float* ap = (const float*)addv + row * ld + col;
    const float4 r0 = *(const float4*)ap;
    const float4 r1 = *(const float4*)(ap + 4);
    x[0] = r0.x + bf2f(a[0]); x[1] = r0.y + bf2f(a[1]);
    x[2] = r0.z + bf2f(a[2]); x[3] = r0.w + bf2f(a[3]);
    x[4] = r1.x + bf2f(a[4]); x[5] = r1.y + bf2f(a[5]);
    x[6] = r1.z + bf2f(a[6]); x[7] = r1.w + bf2f(a[7]);
  }
  float s = 0.f, sq = 0.f;
#pragma unroll
  for (int i = 0; i < 8; ++i) {
    s += x[i];
    sq += x[i] * x[i];
  }
#pragma unroll
  for (int off = 32; off > 0; off >>= 1) {
    s += __shfl_xor(s, off);
    sq += __shfl_xor(sq, off);
  }
  const float mean = s * (1.f / E);
  const float var = sq * (1.f / E) - mean * mean;
  const float rs = rsqrtf(var + LNEPS);
  const float4 g0 = *(const float4*)(g + col);
  const float4 g1 = *(const float4*)(g + col + 4);
  const float4 b0 = *(const float4*)(b + col);
  const float4 b1 = *(const float4*)(b + col + 4);
  float y[8];
  y[0] = (x[0] - mean) * rs * g0.x + b0.x;
  y[1] = (x[1] - mean) * rs * g0.y + b0.y;
  y[2] = (x[2] - mean) * rs * g0.z + b0.z;
  y[3] = (x[3] - mean) * rs * g0.w + b0.w;
  y[4] = (x[4] - mean) * rs * g1.x + b1.x;
  y[5] = (x[5] - mean) * rs * g1.y + b1.y;
  y[6] = (x[6] - mean) * rs * g1.z + b1.z;
  y[7] = (x[7] - mean) * rs * g1.w + b1.w;
  if (MODE == 0) {
    u16x8 o;
#pragma unroll
    for (int i = 0; i < 8; ++i) o[i] = f2bf(y[i]);
    *(u16x8*)((u16*)outp + row * E + col) = o;
  } else {
    float* op = (float*)outp + row * ld + col;
    *(float4*)op = make_float4(y[0], y[1], y[2], y[3]);
    *(float4*)(op + 4) = make_float4(y[4], y[5], y[6], y[7]);
  }
}

__global__ __launch_bounds__(256) void cast_kernel(const float* __restrict__ in,
                                                   u16* __restrict__ out) {
  const size_t i = ((size_t)blockIdx.x * 256 + threadIdx.x) * 8;
  const float4 a = *(const float4*)(in + i);
  const float4 c = *(const float4*)(in + i + 4);
  u16x8 o;
  o[0] = f2bf(a.x); o[1] = f2bf(a.y); o[2] = f2bf(a.z); o[3] = f2bf(a.w);
  o[4] = f2bf(c.x); o[5] = f2bf(c.y); o[6] = f2bf(c.z); o[7] = f2bf(c.w);
  *(u16x8*)(out + i) = o;
}

// out[k][j] = bf16(in[j][k]) for ExE
__global__ __launch_bounds__(256) void transpose_cast_kernel(const float* __restrict__ in,
                                                             u16* __restrict__ out) {
  __shared__ float t[32][33];
  const int bx = blockIdx.x * 32;
  const int by = blockIdx.y * 32;
  const int x = threadIdx.x & 31;
  const int y0 = threadIdx.x >> 5;
#pragma unroll
  for (int y = y0; y < 32; y += 8) t[y][x] = in[(size_t)(by + y) * E + bx + x];
  __syncthreads();
#pragma unroll
  for (int y = y0; y < 32; y += 8) out[(size_t)(bx + y) * E + by + x] = f2bf(t[x][y]);
}

// bc[n] = dot(outw[n,:], bv) + outb[n]
__global__ __launch_bounds__(256) void combine_bias_kernel(const float* __restrict__ outw,
                                                           const float* __restrict__ bv,
                                                           const float* __restrict__ outb,
                                                           float* __restrict__ bc) {
  const int n = blockIdx.x * 256 + threadIdx.x;
  const float* wr = outw + (size_t)n * E;
  float s = 0.f;
  for (int j = 0; j < E; j += 4) {
    const float4 w4 = *(const float4*)(wr + j);
    const float4 v4 = *(const float4*)(bv + j);
    s += w4.x * v4.x + w4.y * v4.y + w4.z * v4.z + w4.w * v4.w;
  }
  bc[n] = s + outb[n];
}

extern "C" void kernel_launch(void* const* d_in, const int* in_sizes, int n_in,
                              void* d_out, int out_size, void* d_ws, size_t ws_size,
                              hipStream_t stream) {
  const float* dna      = (const float*)d_in[0];
  const float* mol      = (const float*)d_in[1];
  const float* a1_in_w  = (const float*)d_in[2];
  const float* a1_in_b  = (const float*)d_in[3];
  const float* a1_out_w = (const float*)d_in[4];
  const float* a1_out_b = (const float*)d_in[5];
  const float* a2_in_w  = (const float*)d_in[6];
  const float* a2_in_b  = (const float*)d_in[7];
  const float* a2_out_w = (const float*)d_in[8];
  const float* a2_out_b = (const float*)d_in[9];
  const float* ln1_g = (const float*)d_in[10];
  const float* ln1_b = (const float*)d_in[11];
  const float* ln2_g = (const float*)d_in[12];
  const float* ln2_b = (const float*)d_in[13];
  const float* ln3_g = (const float*)d_in[14];
  const float* ln3_b = (const float*)d_in[15];
  const float* ln4_g = (const float*)d_in[16];
  const float* ln4_b = (const float*)d_in[17];
  const float* f1_w1 = (const float*)d_in[18];
  const float* f1_b1 = (const float*)d_in[19];
  const float* f1_w2 = (const float*)d_in[20];
  const float* f1_b2 = (const float*)d_in[21];
  const float* f2_w1 = (const float*)d_in[22];
  const float* f2_b1 = (const float*)d_in[23];
  const float* f2_w2 = (const float*)d_in[24];
  const float* f2_b2 = (const float*)d_in[25];

  const int M = in_sizes[0] / E;  // 32768

  char* ws = (char*)d_ws;
  auto bump = [&](size_t sz) {
    char* p = ws;
    ws += (sz + 255) & ~(size_t)255;
    return p;
  };
  u16* wvT1   = (u16*)bump((size_t)E * E * 2);
  u16* wvT2   = (u16*)bump((size_t)E * E * 2);
  u16* outw1b = (u16*)bump((size_t)E * E * 2);
  u16* outw2b = (u16*)bump((size_t)E * E * 2);
  u16* Wc1    = (u16*)bump((size_t)E * E * 2);
  u16* Wc2    = (u16*)bump((size_t)E * E * 2);
  u16* fw11   = (u16*)bump((size_t)2 * E * E * 2);
  u16* fw12   = (u16*)bump((size_t)2 * E * E * 2);
  u16* fw21   = (u16*)bump((size_t)2 * E * E * 2);
  u16* fw22   = (u16*)bump((size_t)2 * E * E * 2);
  float* bc1  = (float*)bump(E * 4);
  float* bc2  = (float*)bump(E * 4);
  u16* X1 = (u16*)bump((size_t)M * E * 2);      // dna_bf, later y1
  u16* X2 = (u16*)bump((size_t)M * E * 2);      // mol_bf, later y2
  u16* Hb = (u16*)bump((size_t)M * 2 * E * 2);  // attnA|attnB, later FFN hidden
  u16* H0 = Hb;
  u16* H1 = Hb + (size_t)M * E;
  float* out_f = (float*)d_out;  // M x 2E, left=dna stream, right=mol stream

  // ---- weight prep (runs every call; ~7 MB of ws) ----
  transpose_cast_kernel<<<dim3(16, 16), 256, 0, stream>>>(a1_in_w + 2 * E * E, wvT1);
  transpose_cast_kernel<<<dim3(16, 16), 256, 0, stream>>>(a2_in_w + 2 * E * E, wvT2);
  cast_kernel<<<E * E / 2048, 256, 0, stream>>>(a1_out_w, outw1b);
  cast_kernel<<<E * E / 2048, 256, 0, stream>>>(a2_out_w, outw2b);
  cast_kernel<<<2 * E * E / 2048, 256, 0, stream>>>(f1_w1, fw11);
  cast_kernel<<<2 * E * E / 2048, 256, 0, stream>>>(f1_w2, fw12);
  cast_kernel<<<2 * E * E / 2048, 256, 0, stream>>>(f2_w1, fw21);
  cast_kernel<<<2 * E * E / 2048, 256, 0, stream>>>(f2_w2, fw22);
  combine_bias_kernel<<<2, 256, 0, stream>>>(a1_out_w, a1_in_b + 2 * E, a1_out_b, bc1);
  combine_bias_kernel<<<2, 256, 0, stream>>>(a2_out_w, a2_in_b + 2 * E, a2_out_b, bc2);
  // Wc[n,k] = sum_j out_w[n,j] * wv[j,k]  via gemm_bt(out_w, wv^T)  (M=N=K=512)
  gemm_bt<false, false><<<dim3(4, 2), 256, 0, stream>>>(outw1b, wvT1, nullptr, Wc1, E, E, E, E);
  gemm_bt<false, false><<<dim3(4, 2), 256, 0, stream>>>(outw2b, wvT2, nullptr, Wc2, E, E, E, E);

  // ---- activations ----  (grid = (N/128, M/256): x = N-tile fastest)
  cast_kernel<<<(int)((size_t)M * E / 2048), 256, 0, stream>>>(dna, X1);
  cast_kernel<<<(int)((size_t)M * E / 2048), 256, 0, stream>>>(mol, X2);
  // attn (softmax==1 -> pure projection with combined weights)
  gemm_bt<false, false><<<dim3(4, M / 256), 256, 0, stream>>>(X2, Wc1, bc1, H0, M, E, E, E);
  gemm_bt<false, false><<<dim3(4, M / 256), 256, 0, stream>>>(X1, Wc2, bc2, H1, M, E, E, E);
  // y = LN(x + attn)  (overwrites the now-dead bf16 input casts)
  ln_add_kernel<0><<<M / 4, 256, 0, stream>>>(dna, H0, ln1_g, ln1_b, X1, E);
  ln_add_kernel<0><<<M / 4, 256, 0, stream>>>(mol, H1, ln2_g, ln2_b, X2, E);
  // stream A FFN + final LN (in-place on d_out left half)
  gemm_bt<true, false><<<dim3(8, M / 256), 256, 0, stream>>>(X1, fw11, f1_b1, Hb, M, 2 * E, E, 2 * E);
  gemm_bt<false, true><<<dim3(4, M / 256), 256, 0, stream>>>(Hb, fw12, f1_b2, out_f, M, E, 2 * E, 2 * E);
  ln_add_kernel<1><<<M / 4, 256, 0, stream>>>(X1, out_f, ln3_g, ln3_b, out_f, 2 * E);
  // stream B FFN + final LN (in-place on d_out right half)
  gemm_bt<true, false><<<dim3(8, M / 256), 256, 0, stream>>>(X2, fw21, f2_b1, Hb, M, 2 * E, E, 2 * E);
  gemm_bt<false, true><<<dim3(4, M / 256), 256, 0, stream>>>(Hb, fw22, f2_b2, out_f + E, M, E, 2 * E, 2 * E);
  ln_add_kernel<1><<<M / 4, 256, 0, stream>>>(X2, out_f + E, ln4_g, ln4_b, out_f + E, 2 * E);
}

// Round 4
// 677.091 us; speedup vs baseline: 1.2229x; 1.1041x over previous
//
#include <hip/hip_runtime.h>
#include <stdint.h>

// CrossAttention seq-len-1: softmax over singleton axis == 1, so attention
// reduces to   attn = x_other @ (out_w @ wv).T + (out_w @ bv + out_b).
// Merged-launch pipeline (A/B streams fused via blockIdx.z/y):
//   prep: transpose2, cast6, combine2, prepGEMM(z=2)
//   cast2 -> attnGEMM(z=2) -> LN0(y=2) -> FFN1(z=2) -> FFN2(z=2,bf16 out) -> LN2(y=2,f32 out)
// 10 launches total (was 19). All GEMMs bf16 MFMA 16x16x32, fp32 accumulate.
//
// GEMM: 256x128 block tile, 4 waves each 64x128. Triple-buffered LDS, prefetch
// depth 2, counted s_waitcnt vmcnt(6) (never 0 in steady state) + raw s_barrier
// in one asm block. s_setprio(1) around the pure-MFMA cluster (T5: pays on
// counted-vmcnt schedules). Grid: x = N-tile (fastest) for A-panel L2 reuse.

#define E 512
#define LNEPS 1e-5f

typedef unsigned short u16;
using u16x8   = __attribute__((ext_vector_type(8))) u16;
using shortx8 = __attribute__((ext_vector_type(8))) short;
using floatx4 = __attribute__((ext_vector_type(4))) float;

__device__ __forceinline__ float bf2f(u16 u) {
  uint32_t x = ((uint32_t)u) << 16;
  return __builtin_bit_cast(float, x);
}
__device__ __forceinline__ u16 f2bf(float f) {  // round-to-nearest-even
  uint32_t x = __builtin_bit_cast(uint32_t, f);
  x += 0x7fffu + ((x >> 16) & 1u);
  return (u16)(x >> 16);
}

__device__ __forceinline__ void gl_lds16(const u16* g, u16* l) {
  // async global->LDS, 16B per lane; LDS dest = wave-uniform base + lane*16
  __builtin_amdgcn_global_load_lds(
      (__attribute__((address_space(1))) uint32_t*)g,
      (__attribute__((address_space(3))) uint32_t*)l, 16, 0, 0);
}

// C[m,n] = sum_k A[m,k]*W[n,k] + bias[n]   (A: MxK bf16, W: NxK bf16 row-major)
// 256x128 block tile, BK=32, 4 waves each 64x128. blockIdx.z selects stream.
template <bool RELU>
__global__ __launch_bounds__(256) void gemm_bt(const u16* __restrict__ A0,
                                               const u16* __restrict__ W0,
                                               const float* __restrict__ bias0,
                                               u16* __restrict__ C0,
                                               const u16* __restrict__ A1,
                                               const u16* __restrict__ W1,
                                               const float* __restrict__ bias1,
                                               u16* __restrict__ C1,
                                               int M, int N, int K, int ldc) {
  // 3 buffers x (A 256x32 = 16KB + B 128x32 = 8KB) = 72 KB
  __shared__ u16 sbuf[3 * 12288];
  const int zz = blockIdx.z;
  const u16* A = zz ? A1 : A0;
  const u16* W = zz ? W1 : W0;
  const float* bias = zz ? bias1 : bias0;
  u16* Cout = zz ? C1 : C0;

  const int tid  = threadIdx.x;
  const int wave = tid >> 6;
  const int lane = tid & 63;
  const int m0 = blockIdx.y * 256;   // M-tile on y
  const int n0 = blockIdx.x * 128;   // N-tile on x (fastest -> A-panel L2 reuse)
  const int wm = wave * 64;
  const int fm   = lane & 15;
  const int quad = lane >> 4;

  const floatx4 zero = {0.f, 0.f, 0.f, 0.f};
  floatx4 acc[4][8];
#pragma unroll
  for (int i = 0; i < 4; ++i)
#pragma unroll
    for (int j = 0; j < 8; ++j) acc[i][j] = zero;

  // staging map (linear LDS, 16B/lane): each issue covers 16 rows x 32 cols.
  const int r4 = lane >> 2;          // 0..15
  const int c0 = (lane & 3) << 3;    // 0,8,16,24
  const u16* ApA = A + (size_t)(m0 + wave * 64 + r4) * K + c0;
  const u16* WpB = W + (size_t)(n0 + wave * 32 + r4) * K + c0;
  const size_t row16 = (size_t)16 * K;
  const int nt = K >> 5;             // BK=32 tiles (16 or 32 here)

  auto STAGE = [&](const u16* ap, const u16* wp, int b) {
    u16* base = sbuf + b * 12288;
#pragma unroll
    for (int q = 0; q < 4; ++q)
      gl_lds16(ap + (size_t)q * row16, base + (wave * 4 + q) * 512);
#pragma unroll
    for (int q = 0; q < 2; ++q)
      gl_lds16(wp + (size_t)q * row16, base + 8192 + (wave * 2 + q) * 512);
  };
  auto COMPUTE = [&](int b) {
    const u16* bA = sbuf + b * 12288;
    const u16* bB = bA + 8192;
    shortx8 af[4], bf[8];
#pragma unroll
    for (int i = 0; i < 4; ++i)
      af[i] = *(const shortx8*)(bA + (wm + i * 16 + fm) * 32 + quad * 8);
#pragma unroll
    for (int j = 0; j < 8; ++j)
      bf[j] = *(const shortx8*)(bB + (j * 16 + fm) * 32 + quad * 8);
    __builtin_amdgcn_s_setprio(1);
#pragma unroll
    for (int j = 0; j < 8; ++j)
#pragma unroll
      for (int i = 0; i < 4; ++i)
        acc[i][j] = __builtin_amdgcn_mfma_f32_16x16x32_bf16(af[i], bf[j], acc[i][j], 0, 0, 0);
    __builtin_amdgcn_s_setprio(0);
  };

  // prologue: tiles 0,1 -> buffers 0,1 (12 loads in flight)
  STAGE(ApA, WpB, 0);
  STAGE(ApA + 32, WpB + 32, 1);
  const u16* As = ApA + 64;
  const u16* Ws = WpB + 64;
  int sb = 2, cb = 0;

  for (int t = 0; t < nt - 1; ++t) {
    // retire tile t's 6 loads (leave tile t+1's 6 in flight), then sync.
    asm volatile("s_waitcnt vmcnt(6)\n\ts_barrier" ::: "memory");
    if (t < nt - 2) {
      STAGE(As, Ws, sb);
      As += 32;
      Ws += 32;
      sb = (sb == 2) ? 0 : sb + 1;
    }
    COMPUTE(cb);
    cb = (cb == 2) ? 0 : cb + 1;
  }
  asm volatile("s_waitcnt vmcnt(0)\n\ts_barrier" ::: "memory");
  COMPUTE(cb);

  // epilogue: C/D layout col=lane&15, row=quad*4+reg  (m89/m91 verified)
#pragma unroll
  for (int j = 0; j < 8; ++j) {
    const int col = n0 + j * 16 + fm;
    const float bj = bias ? bias[col] : 0.f;
#pragma unroll
    for (int i = 0; i < 4; ++i) {
      const int rb = m0 + wm + i * 16 + quad * 4;
#pragma unroll
      for (int r = 0; r < 4; ++r) {
        float v = acc[i][j][r] + bj;
        if (RELU) v = fmaxf(v, 0.f);
        Cout[(size_t)(rb + r) * ldc + col] = f2bf(v);
      }
    }
  }
}

// MODE 0: out_bf16[row*E] = LN(resid_f32[row*E] + add_bf16[row*E])
// MODE 2: out_f32[row*ld] = LN(resid_bf16[row*E] + add_bf16[row*E])
// blockIdx.y selects stream. One wave per row of 512; lane handles 8 elems.
template <int MODE>
__global__ __launch_bounds__(256) void ln_add_kernel(
    const void* __restrict__ resid0, const void* __restrict__ resid1,
    const u16* __restrict__ add0, const u16* __restrict__ add1,
    const float* __restrict__ g0, const float* __restrict__ b0,
    const float* __restrict__ g1, const float* __restrict__ b1,
    void* __restrict__ out0, void* __restrict__ out1, int ld) {
  const int ss = blockIdx.y;
  const void* resid = ss ? resid1 : resid0;
  const u16* addv = ss ? add1 : add0;
  const float* g = ss ? g1 : g0;
  const float* b = ss ? b1 : b0;
  void* outp = ss ? out1 : out0;

  const int wave = threadIdx.x >> 6;
  const int lane = threadIdx.x & 63;
  const size_t row = (size_t)blockIdx.x * 4 + wave;
  const int col = lane * 8;
  float x[8];
  const u16x8 a = *(const u16x8*)(addv + row * E + col);
  if (MODE == 0) {
    const float* rp = (const float*)resid + row * E + col;
    const float4 r0 = *(const float4*)rp;
    const float4 r1 = *(const float4*)(rp + 4);
    x[0] = r0.x + bf2f(a[0]); x[1] = r0.y + bf2f(a[1]);
    x[2] = r0.z + bf2f(a[2]); x[3] = r0.w + bf2f(a[3]);
    x[4] = r1.x + bf2f(a[4]); x[5] = r1.y + bf2f(a[5]);
    x[6] = r1.z + bf2f(a[6]); x[7] = r1.w + bf2f(a[7]);
  } else {
    const u16x8 rr = *(const u16x8*)((const u16*)resid + row * E + col);
#pragma unroll
    for (int i = 0; i < 8; ++i) x[i] = bf2f(rr[i]) + bf2f(a[i]);
  }
  float s = 0.f, sq = 0.f;
#pragma unroll
  for (int i = 0; i < 8; ++i) {
    s += x[i];
    sq += x[i] * x[i];
  }
#pragma unroll
  for (int off = 32; off > 0; off >>= 1) {
    s += __shfl_xor(s, off);
    sq += __shfl_xor(sq, off);
  }
  const float mean = s * (1.f / E);
  const float var = sq * (1.f / E) - mean * mean;
  const float rs = rsqrtf(var + LNEPS);
  const float4 g0v = *(const float4*)(g + col);
  const float4 g1v = *(const float4*)(g + col + 4);
  const float4 b0v = *(const float4*)(b + col);
  const float4 b1v = *(const float4*)(b + col + 4);
  float y[8];
  y[0] = (x[0] - mean) * rs * g0v.x + b0v.x;
  y[1] = (x[1] - mean) * rs * g0v.y + b0v.y;
  y[2] = (x[2] - mean) * rs * g0v.z + b0v.z;
  y[3] = (x[3] - mean) * rs * g0v.w + b0v.w;
  y[4] = (x[4] - mean) * rs * g1v.x + b1v.x;
  y[5] = (x[5] - mean) * rs * g1v.y + b1v.y;
  y[6] = (x[6] - mean) * rs * g1v.z + b1v.z;
  y[7] = (x[7] - mean) * rs * g1v.w + b1v.w;
  if (MODE == 0) {
    u16x8 o;
#pragma unroll
    for (int i = 0; i < 8; ++i) o[i] = f2bf(y[i]);
    *(u16x8*)((u16*)outp + row * E + col) = o;
  } else {
    float* op = (float*)outp + row * ld + col;
    *(float4*)op = make_float4(y[0], y[1], y[2], y[3]);
    *(float4*)(op + 4) = make_float4(y[4], y[5], y[6], y[7]);
  }
}

// two input casts in one launch (blockIdx.y selects)
__global__ __launch_bounds__(256) void cast2_kernel(const float* __restrict__ in0,
                                                    const float* __restrict__ in1,
                                                    u16* __restrict__ o0,
                                                    u16* __restrict__ o1) {
  const float* in = blockIdx.y ? in1 : in0;
  u16* out = blockIdx.y ? o1 : o0;
  const size_t i = ((size_t)blockIdx.x * 256 + threadIdx.x) * 8;
  const float4 a = *(const float4*)(in + i);
  const float4 c = *(const float4*)(in + i + 4);
  u16x8 o;
  o[0] = f2bf(a.x); o[1] = f2bf(a.y); o[2] = f2bf(a.z); o[3] = f2bf(a.w);
  o[4] = f2bf(c.x); o[5] = f2bf(c.y); o[6] = f2bf(c.z); o[7] = f2bf(c.w);
  *(u16x8*)(out + i) = o;
}

// 6 weight casts in one launch: blocks [0,128) s0, [128,256) s1 (E*E each),
// [256,512) s2, [512,768) s3, [768,1024) s4, [1024,1280) s5 (2E*E each... 2E^2)
__global__ __launch_bounds__(256) void cast6_kernel(
    const float* __restrict__ s0, u16* __restrict__ d0,
    const float* __restrict__ s1, u16* __restrict__ d1,
    const float* __restrict__ s2, u16* __restrict__ d2,
    const float* __restrict__ s3, u16* __restrict__ d3,
    const float* __restrict__ s4, u16* __restrict__ d4,
    const float* __restrict__ s5, u16* __restrict__ d5) {
  int b = blockIdx.x;
  const float* in;
  u16* out;
  if (b < 256) {
    in = (b < 128) ? s0 : s1;
    out = (b < 128) ? d0 : d1;
    b &= 127;
  } else {
    const int t = (b - 256) >> 8;  // 0..3
    in = (t == 0) ? s2 : (t == 1) ? s3 : (t == 2) ? s4 : s5;
    out = (t == 0) ? d2 : (t == 1) ? d3 : (t == 2) ? d4 : d5;
    b = (b - 256) & 255;
  }
  const size_t i = ((size_t)b * 256 + threadIdx.x) * 8;
  const float4 a = *(const float4*)(in + i);
  const float4 c = *(const float4*)(in + i + 4);
  u16x8 o;
  o[0] = f2bf(a.x); o[1] = f2bf(a.y); o[2] = f2bf(a.z); o[3] = f2bf(a.w);
  o[4] = f2bf(c.x); o[5] = f2bf(c.y); o[6] = f2bf(c.z); o[7] = f2bf(c.w);
  *(u16x8*)(out + i) = o;
}

// out[k][j] = bf16(in[j][k]) for ExE; blockIdx.z selects stream
__global__ __launch_bounds__(256) void transpose_cast2_kernel(const float* __restrict__ in0,
                                                              u16* __restrict__ out0,
                                                              const float* __restrict__ in1,
                                                              u16* __restrict__ out1) {
  __shared__ float t[32][33];
  const float* in = blockIdx.z ? in1 : in0;
  u16* out = blockIdx.z ? out1 : out0;
  const int bx = blockIdx.x * 32;
  const int by = blockIdx.y * 32;
  const int x = threadIdx.x & 31;
  const int y0 = threadIdx.x >> 5;
#pragma unroll
  for (int y = y0; y < 32; y += 8) t[y][x] = in[(size_t)(by + y) * E + bx + x];
  __syncthreads();
#pragma unroll
  for (int y = y0; y < 32; y += 8) out[(size_t)(bx + y) * E + by + x] = f2bf(t[x][y]);
}

// bc[n] = dot(outw[n,:], bv) + outb[n]; n in [0,1024): n<512 stream A else B
__global__ __launch_bounds__(256) void combine_bias2_kernel(
    const float* __restrict__ outw1, const float* __restrict__ bv1,
    const float* __restrict__ outb1, float* __restrict__ bc1,
    const float* __restrict__ outw2, const float* __restrict__ bv2,
    const float* __restrict__ outb2, float* __restrict__ bc2) {
  int n = blockIdx.x * 256 + threadIdx.x;
  const float* outw = (n < E) ? outw1 : outw2;
  const float* bv = (n < E) ? bv1 : bv2;
  const float* outb = (n < E) ? outb1 : outb2;
  float* bc = (n < E) ? bc1 : bc2;
  n &= (E - 1);
  const float* wr = outw + (size_t)n * E;
  float s = 0.f;
  for (int j = 0; j < E; j += 4) {
    const float4 w4 = *(const float4*)(wr + j);
    const float4 v4 = *(const float4*)(bv + j);
    s += w4.x * v4.x + w4.y * v4.y + w4.z * v4.z + w4.w * v4.w;
  }
  bc[n] = s + outb[n];
}

extern "C" void kernel_launch(void* const* d_in, const int* in_sizes, int n_in,
                              void* d_out, int out_size, void* d_ws, size_t ws_size,
                              hipStream_t stream) {
  const float* dna      = (const float*)d_in[0];
  const float* mol      = (const float*)d_in[1];
  const float* a1_in_w  = (const float*)d_in[2];
  const float* a1_in_b  = (const float*)d_in[3];
  const float* a1_out_w = (const float*)d_in[4];
  const float* a1_out_b = (const float*)d_in[5];
  const float* a2_in_w  = (const float*)d_in[6];
  const float* a2_in_b  = (const float*)d_in[7];
  const float* a2_out_w = (const float*)d_in[8];
  const float* a2_out_b = (const float*)d_in[9];
  const float* ln1_g = (const float*)d_in[10];
  const float* ln1_b = (const float*)d_in[11];
  const float* ln2_g = (const float*)d_in[12];
  const float* ln2_b = (const float*)d_in[13];
  const float* ln3_g = (const float*)d_in[14];
  const float* ln3_b = (const float*)d_in[15];
  const float* ln4_g = (const float*)d_in[16];
  const float* ln4_b = (const float*)d_in[17];
  const float* f1_w1 = (const float*)d_in[18];
  const float* f1_b1 = (const float*)d_in[19];
  const float* f1_w2 = (const float*)d_in[20];
  const float* f1_b2 = (const float*)d_in[21];
  const float* f2_w1 = (const float*)d_in[22];
  const float* f2_b1 = (const float*)d_in[23];
  const float* f2_w2 = (const float*)d_in[24];
  const float* f2_b2 = (const float*)d_in[25];

  const int M = in_sizes[0] / E;  // 32768

  char* ws = (char*)d_ws;
  auto bump = [&](size_t sz) {
    char* p = ws;
    ws += (sz + 255) & ~(size_t)255;
    return p;
  };
  u16* wvT1   = (u16*)bump((size_t)E * E * 2);
  u16* wvT2   = (u16*)bump((size_t)E * E * 2);
  u16* outw1b = (u16*)bump((size_t)E * E * 2);
  u16* outw2b = (u16*)bump((size_t)E * E * 2);
  u16* Wc1    = (u16*)bump((size_t)E * E * 2);
  u16* Wc2    = (u16*)bump((size_t)E * E * 2);
  u16* fw11   = (u16*)bump((size_t)2 * E * E * 2);
  u16* fw12   = (u16*)bump((size_t)2 * E * E * 2);
  u16* fw21   = (u16*)bump((size_t)2 * E * E * 2);
  u16* fw22   = (u16*)bump((size_t)2 * E * E * 2);
  float* bc1  = (float*)bump(E * 4);
  float* bc2  = (float*)bump(E * 4);
  u16* X1  = (u16*)bump((size_t)M * E * 2);      // dna_bf, later y1
  u16* X2  = (u16*)bump((size_t)M * E * 2);      // mol_bf, later y2
  u16* Hb0 = (u16*)bump((size_t)M * 2 * E * 2);  // stream A FFN hidden
  u16* Hb1 = (u16*)bump((size_t)M * 2 * E * 2);  // stream B FFN hidden
  u16* Hc0 = (u16*)bump((size_t)M * E * 2);      // stream A attn out, later FFN2 out
  u16* Hc1 = (u16*)bump((size_t)M * E * 2);      // stream B attn out, later FFN2 out
  float* out_f = (float*)d_out;  // M x 2E, left=dna stream, right=mol stream

  // ---- weight prep (4 launches) ----
  transpose_cast2_kernel<<<dim3(16, 16, 2), 256, 0, stream>>>(
      a1_in_w + 2 * E * E, wvT1, a2_in_w + 2 * E * E, wvT2);
  cast6_kernel<<<1280, 256, 0, stream>>>(a1_out_w, outw1b, a2_out_w, outw2b,
                                         f1_w1, fw11, f1_w2, fw12, f2_w1, fw21, f2_w2, fw22);
  combine_bias2_kernel<<<4, 256, 0, stream>>>(a1_out_w, a1_in_b + 2 * E, a1_out_b, bc1,
                                              a2_out_w, a2_in_b + 2 * E, a2_out_b, bc2);
  // Wc[n,k] = sum_j out_w[n,j] * wv[j,k]  via gemm_bt(out_w, wv^T)  (M=N=K=512)
  gemm_bt<false><<<dim3(4, 2, 2), 256, 0, stream>>>(
      outw1b, wvT1, nullptr, Wc1, outw2b, wvT2, nullptr, Wc2, E, E, E, E);

  // ---- activations (6 launches) ----
  cast2_kernel<<<dim3((unsigned)((size_t)M * E / 2048), 2), 256, 0, stream>>>(dna, mol, X1, X2);
  // attn (softmax==1 -> pure projection with combined weights); A-stream uses X2!
  gemm_bt<false><<<dim3(4, M / 256, 2), 256, 0, stream>>>(
      X2, Wc1, bc1, Hc0, X1, Wc2, bc2, Hc1, M, E, E, E);
  // y = LN(x + attn)  (overwrites the now-dead bf16 input casts)
  ln_add_kernel<0><<<dim3(M / 4, 2), 256, 0, stream>>>(
      dna, mol, Hc0, Hc1, ln1_g, ln1_b, ln2_g, ln2_b, X1, X2, E);
  // FFN hidden (relu)
  gemm_bt<true><<<dim3(8, M / 256, 2), 256, 0, stream>>>(
      X1, fw11, f1_b1, Hb0, X2, fw21, f2_b1, Hb1, M, 2 * E, E, 2 * E);
  // FFN out (bf16, overwrites dead attn buffers)
  gemm_bt<false><<<dim3(4, M / 256, 2), 256, 0, stream>>>(
      Hb0, fw12, f1_b2, Hc0, Hb1, fw22, f2_b2, Hc1, M, E, 2 * E, E);
  // final LN -> f32 d_out halves
  ln_add_kernel<2><<<dim3(M / 4, 2), 256, 0, stream>>>(
      X1, X2, Hc0, Hc1, ln3_g, ln3_b, ln4_g, ln4_b, out_f, out_f + E, 2 * E);
}

// Round 5
// 618.526 us; speedup vs baseline: 1.3386x; 1.0947x over previous
//
#include <hip/hip_runtime.h>
#include <stdint.h>

// CrossAttention seq-len-1: softmax over singleton axis == 1, so attention
// reduces to   attn = x_other @ (out_w @ wv).T + (out_w @ bv + out_b).
// Merged-launch pipeline (A/B streams fused via blockIdx.z/y):
//   prep: transpose2, cast6, combine2, prepGEMM(z=2)
//   cast2 -> attnGEMM(z=2) -> LN0(y=2) -> FFN1(z=2) -> FFN2(z=2,bf16 out) -> LN2(y=2,f32 out)
// 10 launches total. All GEMMs bf16 MFMA 16x16x32, fp32 accumulate.
//
// GEMM: 256x128 block tile, 4 waves each 64x128. Triple-buffered LDS, prefetch
// depth 2, counted s_waitcnt vmcnt(6) (never 0 in steady state) + raw s_barrier
// in one asm block. s_setprio(1) around the pure-MFMA cluster.
// XCD-aware bijective block swizzle (T1): hardware XCD = linear_id % 8; remap so
// each XCD owns a contiguous y-chunk (all N-tiles) of one stream -> each A-panel
// is fetched by exactly ONE XCD's L2 (round-4 counters showed 8x A over-fetch:
// FETCH 265 MB vs ~70 MB ideal because x-tiles sharing a panel round-robined
// across all 8 non-coherent L2s).

#define E 512
#define LNEPS 1e-5f

typedef unsigned short u16;
using u16x8   = __attribute__((ext_vector_type(8))) u16;
using shortx8 = __attribute__((ext_vector_type(8))) short;
using floatx4 = __attribute__((ext_vector_type(4))) float;

__device__ __forceinline__ float bf2f(u16 u) {
  uint32_t x = ((uint32_t)u) << 16;
  return __builtin_bit_cast(float, x);
}
__device__ __forceinline__ u16 f2bf(float f) {  // round-to-nearest-even
  uint32_t x = __builtin_bit_cast(uint32_t, f);
  x += 0x7fffu + ((x >> 16) & 1u);
  return (u16)(x >> 16);
}

__device__ __forceinline__ void gl_lds16(const u16* g, u16* l) {
  // async global->LDS, 16B per lane; LDS dest = wave-uniform base + lane*16
  __builtin_amdgcn_global_load_lds(
      (__attribute__((address_space(1))) uint32_t*)g,
      (__attribute__((address_space(3))) uint32_t*)l, 16, 0, 0);
}

// C[m,n] = sum_k A[m,k]*W[n,k] + bias[n]   (A: MxK bf16, W: NxK bf16 row-major)
// 256x128 block tile, BK=32, 4 waves each 64x128. bz selects stream.
template <bool RELU>
__global__ __launch_bounds__(256) void gemm_bt(const u16* __restrict__ A0,
                                               const u16* __restrict__ W0,
                                               const float* __restrict__ bias0,
                                               u16* __restrict__ C0,
                                               const u16* __restrict__ A1,
                                               const u16* __restrict__ W1,
                                               const float* __restrict__ bias1,
                                               u16* __restrict__ C1,
                                               int M, int N, int K, int ldc) {
  // ---- XCD-aware bijective swizzle (T1) ----
  const int gx = gridDim.x, gy = gridDim.y, gz = gridDim.z;
  const int T = gx * gy * gz;
  const int l = blockIdx.x + gx * (blockIdx.y + gy * blockIdx.z);
  int bx, by, bz;
  if ((T & 7) == 0) {
    const int g = (l & 7) * (T >> 3) + (l >> 3);  // XCD (l&7) owns contiguous g-chunk
    bx = g % gx;
    const int rest = g / gx;
    by = rest % gy;
    bz = rest / gy;
  } else {
    bx = blockIdx.x; by = blockIdx.y; bz = blockIdx.z;
  }

  // 3 buffers x (A 256x32 = 16KB + B 128x32 = 8KB) = 72 KB
  __shared__ u16 sbuf[3 * 12288];
  const u16* A = bz ? A1 : A0;
  const u16* W = bz ? W1 : W0;
  const float* bias = bz ? bias1 : bias0;
  u16* Cout = bz ? C1 : C0;

  const int tid  = threadIdx.x;
  const int wave = tid >> 6;
  const int lane = tid & 63;
  const int m0 = by * 256;   // M-tile
  const int n0 = bx * 128;   // N-tile (fastest within an XCD's chunk -> A-panel L2 reuse)
  const int wm = wave * 64;
  const int fm   = lane & 15;
  const int quad = lane >> 4;

  const floatx4 zero = {0.f, 0.f, 0.f, 0.f};
  floatx4 acc[4][8];
#pragma unroll
  for (int i = 0; i < 4; ++i)
#pragma unroll
    for (int j = 0; j < 8; ++j) acc[i][j] = zero;

  // staging map (linear LDS, 16B/lane): each issue covers 16 rows x 32 cols.
  const int r4 = lane >> 2;          // 0..15
  const int c0 = (lane & 3) << 3;    // 0,8,16,24
  const u16* ApA = A + (size_t)(m0 + wave * 64 + r4) * K + c0;
  const u16* WpB = W + (size_t)(n0 + wave * 32 + r4) * K + c0;
  const size_t row16 = (size_t)16 * K;
  const int nt = K >> 5;             // BK=32 tiles (16 or 32 here)

  auto STAGE = [&](const u16* ap, const u16* wp, int b) {
    u16* base = sbuf + b * 12288;
#pragma unroll
    for (int q = 0; q < 4; ++q)
      gl_lds16(ap + (size_t)q * row16, base + (wave * 4 + q) * 512);
#pragma unroll
    for (int q = 0; q < 2; ++q)
      gl_lds16(wp + (size_t)q * row16, base + 8192 + (wave * 2 + q) * 512);
  };
  auto COMPUTE = [&](int b) {
    const u16* bA = sbuf + b * 12288;
    const u16* bB = bA + 8192;
    shortx8 af[4], bf[8];
#pragma unroll
    for (int i = 0; i < 4; ++i)
      af[i] = *(const shortx8*)(bA + (wm + i * 16 + fm) * 32 + quad * 8);
#pragma unroll
    for (int j = 0; j < 8; ++j)
      bf[j] = *(const shortx8*)(bB + (j * 16 + fm) * 32 + quad * 8);
    __builtin_amdgcn_s_setprio(1);
#pragma unroll
    for (int j = 0; j < 8; ++j)
#pragma unroll
      for (int i = 0; i < 4; ++i)
        acc[i][j] = __builtin_amdgcn_mfma_f32_16x16x32_bf16(af[i], bf[j], acc[i][j], 0, 0, 0);
    __builtin_amdgcn_s_setprio(0);
  };

  // prologue: tiles 0,1 -> buffers 0,1 (12 loads in flight)
  STAGE(ApA, WpB, 0);
  STAGE(ApA + 32, WpB + 32, 1);
  const u16* As = ApA + 64;
  const u16* Ws = WpB + 64;
  int sb = 2, cb = 0;

  for (int t = 0; t < nt - 1; ++t) {
    // retire tile t's 6 loads (leave tile t+1's 6 in flight), then sync.
    asm volatile("s_waitcnt vmcnt(6)\n\ts_barrier" ::: "memory");
    if (t < nt - 2) {
      STAGE(As, Ws, sb);
      As += 32;
      Ws += 32;
      sb = (sb == 2) ? 0 : sb + 1;
    }
    COMPUTE(cb);
    cb = (cb == 2) ? 0 : cb + 1;
  }
  asm volatile("s_waitcnt vmcnt(0)\n\ts_barrier" ::: "memory");
  COMPUTE(cb);

  // epilogue: C/D layout col=lane&15, row=quad*4+reg  (m89/m91 verified)
#pragma unroll
  for (int j = 0; j < 8; ++j) {
    const int col = n0 + j * 16 + fm;
    const float bj = bias ? bias[col] : 0.f;
#pragma unroll
    for (int i = 0; i < 4; ++i) {
      const int rb = m0 + wm + i * 16 + quad * 4;
#pragma unroll
      for (int r = 0; r < 4; ++r) {
        float v = acc[i][j][r] + bj;
        if (RELU) v = fmaxf(v, 0.f);
        Cout[(size_t)(rb + r) * ldc + col] = f2bf(v);
      }
    }
  }
}

// MODE 0: out_bf16[row*E] = LN(resid_f32[row*E] + add_bf16[row*E])
// MODE 2: out_f32[row*ld] = LN(resid_bf16[row*E] + add_bf16[row*E])
// blockIdx.y selects stream. One wave per row of 512; lane handles 8 elems.
template <int MODE>
__global__ __launch_bounds__(256) void ln_add_kernel(
    const void* __restrict__ resid0, const void* __restrict__ resid1,
    const u16* __restrict__ add0, const u16* __restrict__ add1,
    const float* __restrict__ g0, const float* __restrict__ b0,
    const float* __restrict__ g1, const float* __restrict__ b1,
    void* __restrict__ out0, void* __restrict__ out1, int ld) {
  const int ss = blockIdx.y;
  const void* resid = ss ? resid1 : resid0;
  const u16* addv = ss ? add1 : add0;
  const float* g = ss ? g1 : g0;
  const float* b = ss ? b1 : b0;
  void* outp = ss ? out1 : out0;

  const int wave = threadIdx.x >> 6;
  const int lane = threadIdx.x & 63;
  const size_t row = (size_t)blockIdx.x * 4 + wave;
  const int col = lane * 8;
  float x[8];
  const u16x8 a = *(const u16x8*)(addv + row * E + col);
  if (MODE == 0) {
    const float* rp = (const float*)resid + row * E + col;
    const float4 r0 = *(const float4*)rp;
    const float4 r1 = *(const float4*)(rp + 4);
    x[0] = r0.x + bf2f(a[0]); x[1] = r0.y + bf2f(a[1]);
    x[2] = r0.z + bf2f(a[2]); x[3] = r0.w + bf2f(a[3]);
    x[4] = r1.x + bf2f(a[4]); x[5] = r1.y + bf2f(a[5]);
    x[6] = r1.z + bf2f(a[6]); x[7] = r1.w + bf2f(a[7]);
  } else {
    const u16x8 rr = *(const u16x8*)((const u16*)resid + row * E + col);
#pragma unroll
    for (int i = 0; i < 8; ++i) x[i] = bf2f(rr[i]) + bf2f(a[i]);
  }
  float s = 0.f, sq = 0.f;
#pragma unroll
  for (int i = 0; i < 8; ++i) {
    s += x[i];
    sq += x[i] * x[i];
  }
#pragma unroll
  for (int off = 32; off > 0; off >>= 1) {
    s += __shfl_xor(s, off);
    sq += __shfl_xor(sq, off);
  }
  const float mean = s * (1.f / E);
  const float var = sq * (1.f / E) - mean * mean;
  const float rs = rsqrtf(var + LNEPS);
  const float4 g0v = *(const float4*)(g + col);
  const float4 g1v = *(const float4*)(g + col + 4);
  const float4 b0v = *(const float4*)(b + col);
  const float4 b1v = *(const float4*)(b + col + 4);
  float y[8];
  y[0] = (x[0] - mean) * rs * g0v.x + b0v.x;
  y[1] = (x[1] - mean) * rs * g0v.y + b0v.y;
  y[2] = (x[2] - mean) * rs * g0v.z + b0v.z;
  y[3] = (x[3] - mean) * rs * g0v.w + b0v.w;
  y[4] = (x[4] - mean) * rs * g1v.x + b1v.x;
  y[5] = (x[5] - mean) * rs * g1v.y + b1v.y;
  y[6] = (x[6] - mean) * rs * g1v.z + b1v.z;
  y[7] = (x[7] - mean) * rs * g1v.w + b1v.w;
  if (MODE == 0) {
    u16x8 o;
#pragma unroll
    for (int i = 0; i < 8; ++i) o[i] = f2bf(y[i]);
    *(u16x8*)((u16*)outp + row * E + col) = o;
  } else {
    float* op = (float*)outp + row * ld + col;
    *(float4*)op = make_float4(y[0], y[1], y[2], y[3]);
    *(float4*)(op + 4) = make_float4(y[4], y[5], y[6], y[7]);
  }
}

// two input casts in one launch (blockIdx.y selects)
__global__ __launch_bounds__(256) void cast2_kernel(const float* __restrict__ in0,
                                                    const float* __restrict__ in1,
                                                    u16* __restrict__ o0,
                                                    u16* __restrict__ o1) {
  const float* in = blockIdx.y ? in1 : in0;
  u16* out = blockIdx.y ? o1 : o0;
  const size_t i = ((size_t)blockIdx.x * 256 + threadIdx.x) * 8;
  const float4 a = *(const float4*)(in + i);
  const float4 c = *(const float4*)(in + i + 4);
  u16x8 o;
  o[0] = f2bf(a.x); o[1] = f2bf(a.y); o[2] = f2bf(a.z); o[3] = f2bf(a.w);
  o[4] = f2bf(c.x); o[5] = f2bf(c.y); o[6] = f2bf(c.z); o[7] = f2bf(c.w);
  *(u16x8*)(out + i) = o;
}

// 6 weight casts in one launch: blocks [0,128) s0, [128,256) s1 (E*E each),
// [256,512) s2, [512,768) s3, [768,1024) s4, [1024,1280) s5 (2E*E each)
__global__ __launch_bounds__(256) void cast6_kernel(
    const float* __restrict__ s0, u16* __restrict__ d0,
    const float* __restrict__ s1, u16* __restrict__ d1,
    const float* __restrict__ s2, u16* __restrict__ d2,
    const float* __restrict__ s3, u16* __restrict__ d3,
    const float* __restrict__ s4, u16* __restrict__ d4,
    const float* __restrict__ s5, u16* __restrict__ d5) {
  int b = blockIdx.x;
  const float* in;
  u16* out;
  if (b < 256) {
    in = (b < 128) ? s0 : s1;
    out = (b < 128) ? d0 : d1;
    b &= 127;
  } else {
    const int t = (b - 256) >> 8;  // 0..3
    in = (t == 0) ? s2 : (t == 1) ? s3 : (t == 2) ? s4 : s5;
    out = (t == 0) ? d2 : (t == 1) ? d3 : (t == 2) ? d4 : d5;
    b = (b - 256) & 255;
  }
  const size_t i = ((size_t)b * 256 + threadIdx.x) * 8;
  const float4 a = *(const float4*)(in + i);
  const float4 c = *(const float4*)(in + i + 4);
  u16x8 o;
  o[0] = f2bf(a.x); o[1] = f2bf(a.y); o[2] = f2bf(a.z); o[3] = f2bf(a.w);
  o[4] = f2bf(c.x); o[5] = f2bf(c.y); o[6] = f2bf(c.z); o[7] = f2bf(c.w);
  *(u16x8*)(out + i) = o;
}

// out[k][j] = bf16(in[j][k]) for ExE; blockIdx.z selects stream
__global__ __launch_bounds__(256) void transpose_cast2_kernel(const float* __restrict__ in0,
                                                              u16* __restrict__ out0,
                                                              const float* __restrict__ in1,
                                                              u16* __restrict__ out1) {
  __shared__ float t[32][33];
  const float* in = blockIdx.z ? in1 : in0;
  u16* out = blockIdx.z ? out1 : out0;
  const int bx = blockIdx.x * 32;
  const int by = blockIdx.y * 32;
  const int x = threadIdx.x & 31;
  const int y0 = threadIdx.x >> 5;
#pragma unroll
  for (int y = y0; y < 32; y += 8) t[y][x] = in[(size_t)(by + y) * E + bx + x];
  __syncthreads();
#pragma unroll
  for (int y = y0; y < 32; y += 8) out[(size_t)(bx + y) * E + by + x] = f2bf(t[x][y]);
}

// bc[n] = dot(outw[n,:], bv) + outb[n]; n in [0,1024): n<512 stream A else B
__global__ __launch_bounds__(256) void combine_bias2_kernel(
    const float* __restrict__ outw1, const float* __restrict__ bv1,
    const float* __restrict__ outb1, float* __restrict__ bc1,
    const float* __restrict__ outw2, const float* __restrict__ bv2,
    const float* __restrict__ outb2, float* __restrict__ bc2) {
  int n = blockIdx.x * 256 + threadIdx.x;
  const float* outw = (n < E) ? outw1 : outw2;
  const float* bv = (n < E) ? bv1 : bv2;
  const float* outb = (n < E) ? outb1 : outb2;
  float* bc = (n < E) ? bc1 : bc2;
  n &= (E - 1);
  const float* wr = outw + (size_t)n * E;
  float s = 0.f;
  for (int j = 0; j < E; j += 4) {
    const float4 w4 = *(const float4*)(wr + j);
    const float4 v4 = *(const float4*)(bv + j);
    s += w4.x * v4.x + w4.y * v4.y + w4.z * v4.z + w4.w * v4.w;
  }
  bc[n] = s + outb[n];
}

extern "C" void kernel_launch(void* const* d_in, const int* in_sizes, int n_in,
                              void* d_out, int out_size, void* d_ws, size_t ws_size,
                              hipStream_t stream) {
  const float* dna      = (const float*)d_in[0];
  const float* mol      = (const float*)d_in[1];
  const float* a1_in_w  = (const float*)d_in[2];
  const float* a1_in_b  = (const float*)d_in[3];
  const float* a1_out_w = (const float*)d_in[4];
  const float* a1_out_b = (const float*)d_in[5];
  const float* a2_in_w  = (const float*)d_in[6];
  const float* a2_in_b  = (const float*)d_in[7];
  const float* a2_out_w = (const float*)d_in[8];
  const float* a2_out_b = (const float*)d_in[9];
  const float* ln1_g = (const float*)d_in[10];
  const float* ln1_b = (const float*)d_in[11];
  const float* ln2_g = (const float*)d_in[12];
  const float* ln2_b = (const float*)d_in[13];
  const float* ln3_g = (const float*)d_in[14];
  const float* ln3_b = (const float*)d_in[15];
  const float* ln4_g = (const float*)d_in[16];
  const float* ln4_b = (const float*)d_in[17];
  const float* f1_w1 = (const float*)d_in[18];
  const float* f1_b1 = (const float*)d_in[19];
  const float* f1_w2 = (const float*)d_in[20];
  const float* f1_b2 = (const float*)d_in[21];
  const float* f2_w1 = (const float*)d_in[22];
  const float* f2_b1 = (const float*)d_in[23];
  const float* f2_w2 = (const float*)d_in[24];
  const float* f2_b2 = (const float*)d_in[25];

  const int M = in_sizes[0] / E;  // 32768

  char* ws = (char*)d_ws;
  auto bump = [&](size_t sz) {
    char* p = ws;
    ws += (sz + 255) & ~(size_t)255;
    return p;
  };
  u16* wvT1   = (u16*)bump((size_t)E * E * 2);
  u16* wvT2   = (u16*)bump((size_t)E * E * 2);
  u16* outw1b = (u16*)bump((size_t)E * E * 2);
  u16* outw2b = (u16*)bump((size_t)E * E * 2);
  u16* Wc1    = (u16*)bump((size_t)E * E * 2);
  u16* Wc2    = (u16*)bump((size_t)E * E * 2);
  u16* fw11   = (u16*)bump((size_t)2 * E * E * 2);
  u16* fw12   = (u16*)bump((size_t)2 * E * E * 2);
  u16* fw21   = (u16*)bump((size_t)2 * E * E * 2);
  u16* fw22   = (u16*)bump((size_t)2 * E * E * 2);
  float* bc1  = (float*)bump(E * 4);
  float* bc2  = (float*)bump(E * 4);
  u16* X1  = (u16*)bump((size_t)M * E * 2);      // dna_bf, later y1
  u16* X2  = (u16*)bump((size_t)M * E * 2);      // mol_bf, later y2
  u16* Hb0 = (u16*)bump((size_t)M * 2 * E * 2);  // stream A FFN hidden
  u16* Hb1 = (u16*)bump((size_t)M * 2 * E * 2);  // stream B FFN hidden
  u16* Hc0 = (u16*)bump((size_t)M * E * 2);      // stream A attn out, later FFN2 out
  u16* Hc1 = (u16*)bump((size_t)M * E * 2);      // stream B attn out, later FFN2 out
  float* out_f = (float*)d_out;  // M x 2E, left=dna stream, right=mol stream

  // ---- weight prep (4 launches) ----
  transpose_cast2_kernel<<<dim3(16, 16, 2), 256, 0, stream>>>(
      a1_in_w + 2 * E * E, wvT1, a2_in_w + 2 * E * E, wvT2);
  cast6_kernel<<<1280, 256, 0, stream>>>(a1_out_w, outw1b, a2_out_w, outw2b,
                                         f1_w1, fw11, f1_w2, fw12, f2_w1, fw21, f2_w2, fw22);
  combine_bias2_kernel<<<4, 256, 0, stream>>>(a1_out_w, a1_in_b + 2 * E, a1_out_b, bc1,
                                              a2_out_w, a2_in_b + 2 * E, a2_out_b, bc2);
  // Wc[n,k] = sum_j out_w[n,j] * wv[j,k]  via gemm_bt(out_w, wv^T)  (M=N=K=512)
  gemm_bt<false><<<dim3(4, 2, 2), 256, 0, stream>>>(
      outw1b, wvT1, nullptr, Wc1, outw2b, wvT2, nullptr, Wc2, E, E, E, E);

  // ---- activations (6 launches) ----
  cast2_kernel<<<dim3((unsigned)((size_t)M * E / 2048), 2), 256, 0, stream>>>(dna, mol, X1, X2);
  // attn (softmax==1 -> pure projection with combined weights); A-stream uses X2!
  gemm_bt<false><<<dim3(4, M / 256, 2), 256, 0, stream>>>(
      X2, Wc1, bc1, Hc0, X1, Wc2, bc2, Hc1, M, E, E, E);
  // y = LN(x + attn)  (overwrites the now-dead bf16 input casts)
  ln_add_kernel<0><<<dim3(M / 4, 2), 256, 0, stream>>>(
      dna, mol, Hc0, Hc1, ln1_g, ln1_b, ln2_g, ln2_b, X1, X2, E);
  // FFN hidden (relu)
  gemm_bt<true><<<dim3(8, M / 256, 2), 256, 0, stream>>>(
      X1, fw11, f1_b1, Hb0, X2, fw21, f2_b1, Hb1, M, 2 * E, E, 2 * E);
  // FFN out (bf16, overwrites dead attn buffers)
  gemm_bt<false><<<dim3(4, M / 256, 2), 256, 0, stream>>>(
      Hb0, fw12, f1_b2, Hc0, Hb1, fw22, f2_b2, Hc1, M, E, 2 * E, E);
  // final LN -> f32 d_out halves
  ln_add_kernel<2><<<dim3(M / 4, 2), 256, 0, stream>>>(
      X1, X2, Hc0, Hc1, ln3_g, ln3_b, ln4_g, ln4_b, out_f, out_f + E, 2 * E);
}